// Round 8
// baseline (582.587 us; speedup 1.0000x reference)
//
#include <hip/hip_runtime.h>

#define N_NODES 100000
#define N_EDGES 1600000
#define IN_F 32
#define OUT_F 64
#define K_TOTAL 25          // 5x5
#define CAP 31              // bucket capacity; overflow exact via ovf list (~30 edges expected)
#define OVF_CAP 8192

// ---- workspace layout (bytes) ----
// cnt    : int[100000]      @ 0         (400000)
// ovfcnt : int              @ 400000
// WT4    : float[51200]     @ 400064    (204800; 16B aligned; [200][64] float4)
// ovf    : uint4[8192]      @ 604864    (131072; 16B aligned)
// recs   : uint2[100000*31] @ 735936    (24800000; 16B aligned)
#define WS_CNT    0
#define WS_OVFCNT 400000
#define WS_WT4    400064
#define WS_OVF    604864
#define WS_REC    735936
#define WS_NEED   (735936 + (size_t)N_NODES * CAP * 8)   // 25,535,936 (< proven 26.2 MB)

typedef float v2f __attribute__((ext_vector_type(2)));

// =================== build kernels ===================

// (validated) W[j=800][o=64] -> WT4 [jq=200][o=64] float4 over j%4
__global__ __launch_bounds__(256) void transpose_w4(const float* __restrict__ W,
                                                    float* __restrict__ WT4f) {
    int idx = blockIdx.x * 256 + threadIdx.x;      // grid covers 51200 exactly
    int j = idx >> 6, o = idx & 63;
    WT4f[((j >> 2) * 64 + o) * 4 + (j & 3)] = W[idx];
}

// single atomic pass, 2 edges/thread (independent atomic chains overlap latency):
// rec {col | kbase<<20, f0u16 | f1u16<<16} -> bucket; overflow -> exact list
__global__ __launch_bounds__(256) void fill_bucket(const int* __restrict__ ei,
                                                   const float* __restrict__ pseudo,
                                                   int* __restrict__ cnt,
                                                   uint2* __restrict__ recs,
                                                   uint4* __restrict__ ovf,
                                                   int* __restrict__ ovfcnt) {
    int base = blockIdx.x * 512 + threadIdx.x;     // grid*512 covers N_EDGES exactly
#pragma unroll
    for (int h = 0; h < 2; ++h) {
        int e = base + h * 256;
        int row = ei[e];
        int col = ei[N_EDGES + e];
        float2 p = ((const float2*)pseudo)[e];
        float v0 = p.x * 4.0f, v1 = p.y * 4.0f;
        int i0 = min((int)v0, 3);
        int i1 = min((int)v1, 3);
        float f0 = v0 - (float)i0;
        float f1 = v1 - (float)i1;
        unsigned u0 = (unsigned)(f0 * 65535.0f + 0.5f);
        unsigned u1 = (unsigned)(f1 * 65535.0f + 0.5f);
        unsigned rx = (unsigned)col | ((unsigned)(i0 * 5 + i1) << 20);
        unsigned ry = u0 | (u1 << 16);
        int pos = atomicAdd(&cnt[row], 1);
        if (pos < CAP) {
            recs[(size_t)row * CAP + pos] = (uint2){rx, ry};
        } else {
            int j = atomicAdd(ovfcnt, 1);
            if (j < OVF_CAP) ovf[j] = (uint4){(unsigned)row, rx, ry, 0u};
        }
    }
}

// =================== fused accumulate + GEMM ===================
// 512 threads, 16 nodes/block. LDS H[16][800] = 51.2 KB -> 3 blocks/CU = 24 waves/CU.
// Accumulate: 32 threads/node (nn=t>>5, f=t&31, scalar f32/thread); recs prefetched
// 4-deep, x rows 2-deep. LDS RMW bank = f -> conflict-free (2-way across node pair = free).
// GEMM: wave wv in [0,8) -> nodes 2wv,2wv+1 (round-2-validated shape); coalesced WT4 float4.
__global__ __launch_bounds__(512, 4) void fused4(
        const float* __restrict__ x, const float* __restrict__ WT4f,
        const float* __restrict__ bias, const int* __restrict__ cnt,
        const uint2* __restrict__ recs, float* __restrict__ out) {
    __shared__ float Hs[16 * 800];
    const int t = threadIdx.x;

    float4* L4 = (float4*)Hs;
    for (int i = t; i < 3200; i += 512) L4[i] = make_float4(0.f, 0.f, 0.f, 0.f);
    __syncthreads();

    // ---- accumulate ----
    {
        const int nn = t >> 5;
        const int f = t & 31;
        const int n = blockIdx.x * 16 + nn;
        const int num = min(cnt[n], CAP);
        float* __restrict__ hb = Hs + nn * 800 + f;

        if (num > 0) {
            const uint2* __restrict__ rp = recs + (size_t)n * CAP;
            const int last = num - 1;
            uint2 r0 = rp[0];
            uint2 r1 = rp[min(1, last)];
            uint2 r2 = rp[min(2, last)];
            uint2 r3 = rp[min(3, last)];
            float xv0 = x[(size_t)(r0.x & 0xFFFFF) * IN_F + f];
            float xv1 = x[(size_t)(r1.x & 0xFFFFF) * IN_F + f];

            for (int i = 0; i < num; ++i) {
                uint2 r4 = rp[min(i + 4, last)];
                float xn = x[(size_t)(r2.x & 0xFFFFF) * IN_F + f];

                float f0 = (float)(r0.y & 0xFFFF) * (1.0f / 65535.0f);
                float f1 = (float)(r0.y >> 16) * (1.0f / 65535.0f);
                float a0 = 1.0f - f0, a1 = 1.0f - f1;
                float b0 = a0 * a1, b1 = a0 * f1, b2 = f0 * a1, b3 = f0 * f1;
                float* __restrict__ p = hb + ((r0.x >> 20) << 5);   // kbase*32 floats

                p[0]   += b0 * xv0;
                p[32]  += b1 * xv0;
                p[160] += b2 * xv0;
                p[192] += b3 * xv0;

                r0 = r1; r1 = r2; r2 = r3; r3 = r4;
                xv0 = xv1; xv1 = xn;
            }
        }
    }
    __syncthreads();

    // ---- GEMM: out[16 x 64] = H[16 x 800] * W[800 x 64] + bias ----
    {
        const int o = t & 63;
        const int wv = t >> 6;                     // 0..7 -> nodes 2wv, 2wv+1
        const float4* __restrict__ wt = ((const float4*)WT4f) + o;
        const float* __restrict__ h0 = Hs + (2 * wv) * 800;
        const float* __restrict__ h1 = h0 + 800;

        v2f acc0a = (v2f)0.0f, acc0b = (v2f)0.0f;
        v2f acc1a = (v2f)0.0f, acc1b = (v2f)0.0f;

        for (int jq = 0; jq < 200; ++jq) {
            float4 w4 = wt[jq * 64];
            v2f wa = {w4.x, w4.y}, wb = {w4.z, w4.w};
            float4 a4 = *(const float4*)(h0 + jq * 4);
            float4 c4 = *(const float4*)(h1 + jq * 4);
            v2f aa = {a4.x, a4.y}, ab = {a4.z, a4.w};
            v2f ca = {c4.x, c4.y}, cb = {c4.z, c4.w};
            acc0a += aa * wa; acc0b += ab * wb;
            acc1a += ca * wa; acc1b += cb * wb;
        }
        float bo = bias[o];
        float* __restrict__ op = out + ((size_t)blockIdx.x * 16 + 2 * wv) * 64 + o;
        op[0]  = bo + acc0a.x + acc0a.y + acc0b.x + acc0b.y;
        op[64] = bo + acc1a.x + acc1a.y + acc1b.x + acc1b.y;
    }
}

// exact fix-up for bucket-overflow edges (expected ~tens); atomic-adds after fused4
__global__ __launch_bounds__(256) void ovf_fix(const float* __restrict__ x,
                                               const float* __restrict__ W,
                                               const uint4* __restrict__ ovf,
                                               const int* __restrict__ ovfcnt,
                                               float* __restrict__ out) {
    const int lane = threadIdx.x & 63;
    const int wv = threadIdx.x >> 6;
    int m = min(*ovfcnt, OVF_CAP);
    for (int idx = wv; idx < m; idx += 4) {
        uint4 v = ovf[idx];
        int row = (int)v.x;
        int col = (int)(v.y & 0xFFFFF);
        int kbase = (int)(v.y >> 20);
        float f0 = (float)(v.z & 0xFFFF) * (1.0f / 65535.0f);
        float f1 = (float)(v.z >> 16) * (1.0f / 65535.0f);
        float a0 = 1.0f - f0, a1 = 1.0f - f1;
        float bb[4] = {a0 * a1, a0 * f1, f0 * a1, f0 * f1};
        const int dk[4] = {0, 1, 5, 6};
        float acc = 0.0f;
#pragma unroll
        for (int s = 0; s < 4; ++s) {
            const float* __restrict__ Wk = W + (size_t)(kbase + dk[s]) * (IN_F * OUT_F);
            float part = 0.0f;
            for (int i = 0; i < IN_F; ++i)
                part += x[(size_t)col * IN_F + i] * Wk[i * OUT_F + lane];
            acc += bb[s] * part;
        }
        atomicAdd(&out[(size_t)row * OUT_F + lane], acc);
    }
}

// =================== direct fallback (tiny ws; validated round 1) ===================

__device__ __forceinline__ void basis_from(float p0, float p1, float b[4], int k[4]) {
    float v0 = p0 * 4.0f, v1 = p1 * 4.0f;
    int i0 = min(max((int)floorf(v0), 0), 3);
    int i1 = min(max((int)floorf(v1), 0), 3);
    float f0 = v0 - (float)i0, f1 = v1 - (float)i1;
    float a00 = 1.0f - f0, a10 = 1.0f - f1;
    b[0] = a00 * a10; k[0] = i0 * 5 + i1;
    b[1] = a00 * f1;  k[1] = i0 * 5 + i1 + 1;
    b[2] = f0 * a10;  k[2] = (i0 + 1) * 5 + i1;
    b[3] = f0 * f1;   k[3] = (i0 + 1) * 5 + i1 + 1;
}

__global__ __launch_bounds__(256) void bias_init(const float* __restrict__ bias,
                                                 float* __restrict__ out) {
    int idx = blockIdx.x * 256 + threadIdx.x;
    if (idx < N_NODES * OUT_F) out[idx] = bias[idx & 63];
}

__global__ __launch_bounds__(256) void spline_direct(
        const float* __restrict__ x, const float* __restrict__ pseudo,
        const int* __restrict__ ei, const float* __restrict__ W,
        float* __restrict__ out) {
    int gtid = blockIdx.x * 256 + threadIdx.x;
    int e = gtid >> 6;
    int lane = threadIdx.x & 63;
    if (e >= N_EDGES) return;
    int row = ei[e];
    int col = ei[N_EDGES + e];
    float b[4]; int k[4];
    basis_from(pseudo[e * 2 + 0], pseudo[e * 2 + 1], b, k);
    float xv = x[col * IN_F + (lane & 31)];
    float acc = 0.0f;
#pragma unroll
    for (int s = 0; s < 4; ++s) {
        const float* __restrict__ Wk = W + k[s] * (IN_F * OUT_F);
        float part = 0.0f;
#pragma unroll
        for (int i = 0; i < IN_F; ++i) {
            float xi = __shfl(xv, i, 64);
            part += xi * Wk[i * OUT_F + lane];
        }
        acc += b[s] * part;
    }
    atomicAdd(&out[row * OUT_F + lane], acc);
}

extern "C" void kernel_launch(void* const* d_in, const int* in_sizes, int n_in,
                              void* d_out, int out_size, void* d_ws, size_t ws_size,
                              hipStream_t stream) {
    const float* features = (const float*)d_in[0];   // [100000, 32]
    const float* pseudo   = (const float*)d_in[1];   // [1600000, 2]
    const int*   eidx     = (const int*)d_in[2];     // [2, 1600000]
    const float* weight   = (const float*)d_in[3];   // [5,5,32,64] -> [800,64]
    const float* bias     = (const float*)d_in[4];   // [64]
    float* out = (float*)d_out;

    char* ws = (char*)d_ws;

    if (ws_size >= WS_NEED) {
        int*   cnt    = (int*)(ws + WS_CNT);
        int*   ovfcnt = (int*)(ws + WS_OVFCNT);
        float* WT4f   = (float*)(ws + WS_WT4);
        uint4* ovf    = (uint4*)(ws + WS_OVF);
        uint2* recs   = (uint2*)(ws + WS_REC);

        hipMemsetAsync(cnt, 0, 400016, stream);      // cnt + ovfcnt
        transpose_w4<<<200, 256, 0, stream>>>(weight, WT4f);
        fill_bucket<<<N_EDGES / 512, 256, 0, stream>>>(eidx, pseudo, cnt, recs, ovf, ovfcnt);
        fused4<<<N_NODES / 16, 512, 0, stream>>>(features, WT4f, bias, cnt, recs, out);
        ovf_fix<<<1, 256, 0, stream>>>(features, weight, ovf, ovfcnt, out);
    } else {
        int blocks = (N_NODES * OUT_F + 255) / 256;
        bias_init<<<blocks, 256, 0, stream>>>(bias, out);
        long long total = (long long)N_EDGES * 64;
        spline_direct<<<(int)((total + 255) / 256), 256, 0, stream>>>(
            features, pseudo, eidx, weight, out);
    }
}

// Round 9
// 552.153 us; speedup vs baseline: 1.0551x; 1.0551x over previous
//
#include <hip/hip_runtime.h>

#define N_NODES 100000
#define N_EDGES 1600000
#define IN_F 32
#define OUT_F 64
#define K_TOTAL 25          // 5x5
#define CAP 31              // bucket capacity; overflow exact via ovf list (~30 edges expected)
#define OVF_CAP 8192

// ---- workspace layout (bytes) ----
// cnt    : int[100000]      @ 0         (400000)
// ovfcnt : int              @ 400000
// WQ     : float[51200]     @ 400064    (204800; 16B aligned; [400][32] float4 o-pair layout)
// ovf    : uint4[8192]      @ 604864    (131072; 16B aligned)
// recs   : uint2[100000*31] @ 735936    (24800000; 16B aligned)
#define WS_CNT    0
#define WS_OVFCNT 400000
#define WS_WQ     400064
#define WS_OVF    604864
#define WS_REC    735936
#define WS_NEED   (735936 + (size_t)N_NODES * CAP * 8)   // 25,535,936 (< proven 26.2 MB)

typedef float v2f __attribute__((ext_vector_type(2)));

// =================== build kernels ===================

// W[j=800][o=64] -> WQ: float4[(jq*2+jh)*32 + oo] = {W[j][oo], W[j][oo+32], W[j+1][oo], W[j+1][oo+32]}
// where j = 4*jq + 2*jh. One thread per (j, oo) writes a float2 half.
__global__ __launch_bounds__(256) void pack_wq(const float* __restrict__ W,
                                               float* __restrict__ WQ) {
    int idx = blockIdx.x * 256 + threadIdx.x;      // grid covers 25600 exactly
    int j = idx >> 5, oo = idx & 31;
    float w0 = W[j * 64 + oo];
    float w1 = W[j * 64 + oo + 32];
    int jq = j >> 2, jr = j & 3, jh = jr >> 1, jp = jr & 1;
    ((float2*)WQ)[((jq * 2 + jh) * 32 + oo) * 2 + jp] = make_float2(w0, w1);
}

// single atomic pass, 2 edges/thread: rec {col | kbase<<20, f0u16 | f1u16<<16} -> bucket;
// overflow -> exact list
__global__ __launch_bounds__(256) void fill_bucket(const int* __restrict__ ei,
                                                   const float* __restrict__ pseudo,
                                                   int* __restrict__ cnt,
                                                   uint2* __restrict__ recs,
                                                   uint4* __restrict__ ovf,
                                                   int* __restrict__ ovfcnt) {
    int base = blockIdx.x * 512 + threadIdx.x;     // grid*512 covers N_EDGES exactly
#pragma unroll
    for (int h = 0; h < 2; ++h) {
        int e = base + h * 256;
        int row = ei[e];
        int col = ei[N_EDGES + e];
        float2 p = ((const float2*)pseudo)[e];
        float v0 = p.x * 4.0f, v1 = p.y * 4.0f;
        int i0 = min((int)v0, 3);
        int i1 = min((int)v1, 3);
        float f0 = v0 - (float)i0;
        float f1 = v1 - (float)i1;
        unsigned u0 = (unsigned)(f0 * 65535.0f + 0.5f);
        unsigned u1 = (unsigned)(f1 * 65535.0f + 0.5f);
        unsigned rx = (unsigned)col | ((unsigned)(i0 * 5 + i1) << 20);
        unsigned ry = u0 | (u1 << 16);
        int pos = atomicAdd(&cnt[row], 1);
        if (pos < CAP) {
            recs[(size_t)row * CAP + pos] = (uint2){rx, ry};
        } else {
            int j = atomicAdd(ovfcnt, 1);
            if (j < OVF_CAP) ovf[j] = (uint4){(unsigned)row, rx, ry, 0u};
        }
    }
}

// =================== fused accumulate + GEMM ===================
// 256 threads, 16 nodes/block. LDS H[16][800] = 51.2 KB -> 3 blocks/CU.
// Accumulate (round-7 VALIDATED, verbatim): 16 threads/node (nn=t>>4, fp=t&15, float2),
//   recs prefetched 4-deep, x rows 2-deep.
// GEMM: 2 nodes x 2 outputs per lane. lane = nh*32 + oo; wave wv -> nodes
//   {4wv+nh, 4wv+2+nh}; outputs {oo, oo+32}. H reads: 2 instrs/jq, each 2-address
//   32-lane broadcast (addresses 1600 apart = same banks = free 2-way). 8 pk-fma/jq.
__global__ __launch_bounds__(256, 3) void fused4(
        const float* __restrict__ x, const float* __restrict__ WQ,
        const float* __restrict__ bias, const int* __restrict__ cnt,
        const uint2* __restrict__ recs, float* __restrict__ out) {
    __shared__ float Hs[16 * 800];
    const int t = threadIdx.x;

    float4* L4 = (float4*)Hs;
    for (int i = t; i < 3200; i += 256) L4[i] = make_float4(0.f, 0.f, 0.f, 0.f);
    __syncthreads();

    // ---- accumulate (validated round 7) ----
    {
        const int nn = t >> 4;
        const int fp = t & 15;
        const int n = blockIdx.x * 16 + nn;
        const int num = min(cnt[n], CAP);
        float* __restrict__ hb = Hs + nn * 800 + 2 * fp;

        if (num > 0) {
            const uint2* __restrict__ rp = recs + (size_t)n * CAP;
            const int last = num - 1;
            uint2 r0 = rp[0];
            uint2 r1 = rp[min(1, last)];
            uint2 r2 = rp[min(2, last)];
            uint2 r3 = rp[min(3, last)];
            float2 xv0 = *(const float2*)(x + (size_t)(r0.x & 0xFFFFF) * IN_F + 2 * fp);
            float2 xv1 = *(const float2*)(x + (size_t)(r1.x & 0xFFFFF) * IN_F + 2 * fp);

            for (int i = 0; i < num; ++i) {
                uint2 r4 = rp[min(i + 4, last)];
                float2 xn = *(const float2*)(x + (size_t)(r2.x & 0xFFFFF) * IN_F + 2 * fp);

                float f0 = (float)(r0.y & 0xFFFF) * (1.0f / 65535.0f);
                float f1 = (float)(r0.y >> 16) * (1.0f / 65535.0f);
                float a0 = 1.0f - f0, a1 = 1.0f - f1;
                float b0 = a0 * a1, b1 = a0 * f1, b2 = f0 * a1, b3 = f0 * f1;
                float* __restrict__ p = hb + ((r0.x >> 20) << 5);   // kbase*32 floats

                float2 h;
                h = *(float2*)(p);       h.x += b0 * xv0.x; h.y += b0 * xv0.y; *(float2*)(p)       = h;
                h = *(float2*)(p + 32);  h.x += b1 * xv0.x; h.y += b1 * xv0.y; *(float2*)(p + 32)  = h;
                h = *(float2*)(p + 160); h.x += b2 * xv0.x; h.y += b2 * xv0.y; *(float2*)(p + 160) = h;
                h = *(float2*)(p + 192); h.x += b3 * xv0.x; h.y += b3 * xv0.y; *(float2*)(p + 192) = h;

                r0 = r1; r1 = r2; r2 = r3; r3 = r4;
                xv0 = xv1; xv1 = xn;
            }
        }
    }
    __syncthreads();

    // ---- GEMM: out[16 x 64] = H[16 x 800] * W[800 x 64] + bias ----
    {
        const int lane = t & 63;
        const int wv = t >> 6;
        const int oo = lane & 31;
        const int nh = lane >> 5;
        const int nA = 4 * wv + nh;
        const int nB = nA + 2;
        const float* __restrict__ hA = Hs + nA * 800;
        const float* __restrict__ hB = Hs + nB * 800;
        const float4* __restrict__ wq = ((const float4*)WQ) + oo;

        v2f accA0 = (v2f)0.0f, accA1 = (v2f)0.0f;   // node A, o-pairs (even/odd j split)
        v2f accB0 = (v2f)0.0f, accB1 = (v2f)0.0f;

        for (int jq = 0; jq < 200; ++jq) {
            float4 w0 = wq[(jq * 2 + 0) * 32];      // {W[j][oL],W[j][oH],W[j+1][oL],W[j+1][oH]}
            float4 w1 = wq[(jq * 2 + 1) * 32];      // j+2, j+3
            float4 a4 = *(const float4*)(hA + jq * 4);
            float4 b4 = *(const float4*)(hB + jq * 4);

            accA0 += (v2f){a4.x, a4.x} * (v2f){w0.x, w0.y};
            accA1 += (v2f){a4.y, a4.y} * (v2f){w0.z, w0.w};
            accA0 += (v2f){a4.z, a4.z} * (v2f){w1.x, w1.y};
            accA1 += (v2f){a4.w, a4.w} * (v2f){w1.z, w1.w};
            accB0 += (v2f){b4.x, b4.x} * (v2f){w0.x, w0.y};
            accB1 += (v2f){b4.y, b4.y} * (v2f){w0.z, w0.w};
            accB0 += (v2f){b4.z, b4.z} * (v2f){w1.x, w1.y};
            accB1 += (v2f){b4.w, b4.w} * (v2f){w1.z, w1.w};
        }
        float bL = bias[oo];
        float bH = bias[oo + 32];
        float* __restrict__ outb = out + (size_t)blockIdx.x * 16 * 64;
        outb[nA * 64 + oo]      = bL + accA0.x + accA1.x;
        outb[nA * 64 + oo + 32] = bH + accA0.y + accA1.y;
        outb[nB * 64 + oo]      = bL + accB0.x + accB1.x;
        outb[nB * 64 + oo + 32] = bH + accB0.y + accB1.y;
    }
}

// exact fix-up for bucket-overflow edges (expected ~tens); atomic-adds after fused4
__global__ __launch_bounds__(256) void ovf_fix(const float* __restrict__ x,
                                               const float* __restrict__ W,
                                               const uint4* __restrict__ ovf,
                                               const int* __restrict__ ovfcnt,
                                               float* __restrict__ out) {
    const int lane = threadIdx.x & 63;
    const int wv = threadIdx.x >> 6;
    int m = min(*ovfcnt, OVF_CAP);
    for (int idx = wv; idx < m; idx += 4) {
        uint4 v = ovf[idx];
        int row = (int)v.x;
        int col = (int)(v.y & 0xFFFFF);
        int kbase = (int)(v.y >> 20);
        float f0 = (float)(v.z & 0xFFFF) * (1.0f / 65535.0f);
        float f1 = (float)(v.z >> 16) * (1.0f / 65535.0f);
        float a0 = 1.0f - f0, a1 = 1.0f - f1;
        float bb[4] = {a0 * a1, a0 * f1, f0 * a1, f0 * f1};
        const int dk[4] = {0, 1, 5, 6};
        float acc = 0.0f;
#pragma unroll
        for (int s = 0; s < 4; ++s) {
            const float* __restrict__ Wk = W + (size_t)(kbase + dk[s]) * (IN_F * OUT_F);
            float part = 0.0f;
            for (int i = 0; i < IN_F; ++i)
                part += x[(size_t)col * IN_F + i] * Wk[i * OUT_F + lane];
            acc += bb[s] * part;
        }
        atomicAdd(&out[(size_t)row * OUT_F + lane], acc);
    }
}

// =================== direct fallback (tiny ws; validated round 1) ===================

__device__ __forceinline__ void basis_from(float p0, float p1, float b[4], int k[4]) {
    float v0 = p0 * 4.0f, v1 = p1 * 4.0f;
    int i0 = min(max((int)floorf(v0), 0), 3);
    int i1 = min(max((int)floorf(v1), 0), 3);
    float f0 = v0 - (float)i0, f1 = v1 - (float)i1;
    float a00 = 1.0f - f0, a10 = 1.0f - f1;
    b[0] = a00 * a10; k[0] = i0 * 5 + i1;
    b[1] = a00 * f1;  k[1] = i0 * 5 + i1 + 1;
    b[2] = f0 * a10;  k[2] = (i0 + 1) * 5 + i1;
    b[3] = f0 * f1;   k[3] = (i0 + 1) * 5 + i1 + 1;
}

__global__ __launch_bounds__(256) void bias_init(const float* __restrict__ bias,
                                                 float* __restrict__ out) {
    int idx = blockIdx.x * 256 + threadIdx.x;
    if (idx < N_NODES * OUT_F) out[idx] = bias[idx & 63];
}

__global__ __launch_bounds__(256) void spline_direct(
        const float* __restrict__ x, const float* __restrict__ pseudo,
        const int* __restrict__ ei, const float* __restrict__ W,
        float* __restrict__ out) {
    int gtid = blockIdx.x * 256 + threadIdx.x;
    int e = gtid >> 6;
    int lane = threadIdx.x & 63;
    if (e >= N_EDGES) return;
    int row = ei[e];
    int col = ei[N_EDGES + e];
    float b[4]; int k[4];
    basis_from(pseudo[e * 2 + 0], pseudo[e * 2 + 1], b, k);
    float xv = x[col * IN_F + (lane & 31)];
    float acc = 0.0f;
#pragma unroll
    for (int s = 0; s < 4; ++s) {
        const float* __restrict__ Wk = W + k[s] * (IN_F * OUT_F);
        float part = 0.0f;
#pragma unroll
        for (int i = 0; i < IN_F; ++i) {
            float xi = __shfl(xv, i, 64);
            part += xi * Wk[i * OUT_F + lane];
        }
        acc += b[s] * part;
    }
    atomicAdd(&out[row * OUT_F + lane], acc);
}

extern "C" void kernel_launch(void* const* d_in, const int* in_sizes, int n_in,
                              void* d_out, int out_size, void* d_ws, size_t ws_size,
                              hipStream_t stream) {
    const float* features = (const float*)d_in[0];   // [100000, 32]
    const float* pseudo   = (const float*)d_in[1];   // [1600000, 2]
    const int*   eidx     = (const int*)d_in[2];     // [2, 1600000]
    const float* weight   = (const float*)d_in[3];   // [5,5,32,64] -> [800,64]
    const float* bias     = (const float*)d_in[4];   // [64]
    float* out = (float*)d_out;

    char* ws = (char*)d_ws;

    if (ws_size >= WS_NEED) {
        int*   cnt    = (int*)(ws + WS_CNT);
        int*   ovfcnt = (int*)(ws + WS_OVFCNT);
        float* WQ     = (float*)(ws + WS_WQ);
        uint4* ovf    = (uint4*)(ws + WS_OVF);
        uint2* recs   = (uint2*)(ws + WS_REC);

        hipMemsetAsync(cnt, 0, 400016, stream);      // cnt + ovfcnt
        pack_wq<<<100, 256, 0, stream>>>(weight, WQ);
        fill_bucket<<<N_EDGES / 512, 256, 0, stream>>>(eidx, pseudo, cnt, recs, ovf, ovfcnt);
        fused4<<<N_NODES / 16, 256, 0, stream>>>(features, WQ, bias, cnt, recs, out);
        ovf_fix<<<1, 256, 0, stream>>>(features, weight, ovf, ovfcnt, out);
    } else {
        int blocks = (N_NODES * OUT_F + 255) / 256;
        bias_init<<<blocks, 256, 0, stream>>>(bias, out);
        long long total = (long long)N_EDGES * 64;
        spline_direct<<<(int)((total + 255) / 256), 256, 0, stream>>>(
            features, pseudo, eidx, weight, out);
    }
}